// Round 5
// baseline (6755.135 us; speedup 1.0000x reference)
//
#include <hip/hip_runtime.h>
#include <hip/hip_bf16.h>
#include <math.h>

#define NB 4
#define CE 384
#define NH 12
#define DH 32
#define NPTS 9
#define NLAYERS 2
#define KFG 20
#define KBG 50
#define NITER 10
#define HDIM 64
#define WDIM 64
#define NPIX 4096
#define TWO_PI 6.283185307179586f

typedef __attribute__((ext_vector_type(8))) short short8;
typedef __attribute__((ext_vector_type(4))) float float4v;

static __device__ __forceinline__ unsigned short f2bf(float f) {
  __hip_bfloat16 h = __float2bfloat16(f);
  return *reinterpret_cast<unsigned short*>(&h);
}
static __device__ __forceinline__ float bf2f(unsigned short u) {
  unsigned x = ((unsigned)u) << 16;
  return __uint_as_float(x);
}

// ---------------- masks ----------------
__global__ void k_masks(const float* __restrict__ pm, const float* __restrict__ sm,
                        float* padf, float* objf, float* notp, float* wfg, float* wbg) {
  int i = blockIdx.x * 256 + threadIdx.x;
  if (i >= NB * NPIX) return;
  float p  = (pm[i] == 255.0f) ? 1.f : 0.f;
  float o  = (sm[i] == 1.0f) ? 1.f : 0.f;
  float np_ = 1.f - p;
  padf[i] = p; objf[i] = o; notp[i] = np_;
  wfg[i] = o * np_;
  wbg[i] = (1.f - o) * np_;
}

// ---------------- transpose s_x [B,C,N] -> X [B,N,C] ----------------
__global__ void k_transpose(const float* __restrict__ sx, float* __restrict__ X) {
  long i = (long)blockIdx.x * 256 + threadIdx.x;
  if (i >= (long)NB * NPIX * CE) return;
  int c = (int)(i % CE);
  long r = i / CE;
  int n = (int)(r % NPIX);
  int b = (int)(r / NPIX);
  X[i] = sx[((long)b * CE + c) * NPIX + n];
}

// ---------------- xsq (fp64) ----------------
__global__ void k_xsq(const float* __restrict__ X, double* __restrict__ xsq) {
  int row = blockIdx.x; int t = threadIdx.x;
  const float* xr = X + (long)row * CE;
  double s = 0.0;
  for (int i = t; i < CE; i += 64) { double v = (double)xr[i]; s += v * v; }
  #pragma unroll
  for (int o = 32; o > 0; o >>= 1) s += __shfl_down(s, o, 64);
  if (t == 0) xsq[row] = s;
}

// ---------------- sine positional encoding ----------------
__global__ void k_pos(const float* __restrict__ padf, float* __restrict__ POS) {
  int b = blockIdx.x / HDIM, hh = blockIdx.x % HDIM;
  __shared__ float xv[WDIM], yv[WDIM];
  int t = threadIdx.x;
  if (t < WDIM) {
    int w = t;
    float cum = 0.f, tot = 0.f;
    for (int h2 = 0; h2 < HDIM; ++h2) {
      float nm = 1.f - padf[b * NPIX + h2 * WDIM + w];
      tot += nm;
      if (h2 <= hh) cum += nm;
    }
    yv[w] = cum / (tot + 1e-6f) * TWO_PI;
    float rtot = 0.f, myc = 0.f;
    for (int w2 = 0; w2 < WDIM; ++w2) {
      float nm = 1.f - padf[b * NPIX + hh * WDIM + w2];
      rtot += nm;
      if (w2 <= w) myc += nm;
    }
    xv[w] = myc / (rtot + 1e-6f) * TWO_PI;
  }
  __syncthreads();
  const int nf = CE / 2;  // 192
  for (int i = t; i < WDIM * CE; i += 256) {
    int w = i / CE, c = i % CE;
    int tt = (c < nf) ? c : c - nf;
    float p = (c < nf) ? yv[w] : xv[w];
    float dt = powf(10000.0f, (float)(2 * (tt / 2)) / (float)nf);
    float v = p / dt;
    float r = (tt & 1) ? cosf(v) : sinf(v);
    POS[((long)(b * NPIX + hh * WDIM)) * CE + i] = r;
  }
}

// ---------------- kmeans init ----------------
__global__ void k_kinit(const float* __restrict__ X, const float* __restrict__ wts,
                        double* __restrict__ cen, int K) {
  int b = blockIdx.x;
  __shared__ int idx[KBG];
  if (threadIdx.x == 0) {
    int cnt = 0;
    for (int n = 0; n < NPIX && cnt < K; ++n) if (wts[b * NPIX + n] > 0.f) idx[cnt++] = n;
    for (int n = 0; n < NPIX && cnt < K; ++n) if (!(wts[b * NPIX + n] > 0.f)) idx[cnt++] = n;
  }
  __syncthreads();
  for (int i = threadIdx.x; i < K * CE; i += blockDim.x) {
    int k = i / CE, c = i % CE;
    cen[((long)b * K + k) * CE + c] = (double)X[((long)b * NPIX + idx[k]) * CE + c];
  }
}

__global__ void k_zero_dual(double* __restrict__ z, long total) {
  long i = (long)blockIdx.x * 256 + threadIdx.x;
  if (i < total) z[i] = 0.0;
}

// ---------------- kmeans assign: scalar-load centers, register x, no LDS dot ----------------
template <int K, int KC>
static __device__ __forceinline__ void assign_impl(
    const float* __restrict__ X, const float* __restrict__ wts,
    const double* __restrict__ xsq, const double* __restrict__ cen,
    int* __restrict__ assign, double* __restrict__ den,
    double* csq_s, int* hist_s) {
  int b = blockIdx.y;
  int t = threadIdx.x;
  int n = blockIdx.x * 256 + t;
  const double* cb = cen + (long)b * K * CE;
  if (t < K) {
    double s = 0.0;
    for (int c = 0; c < CE; ++c) { double v = cb[t * CE + c]; s += v * v; }
    csq_s[t] = s;
    hist_s[t] = 0;
  }
  __syncthreads();
  const float* xr = X + ((long)b * NPIX + n) * CE;
  double myxsq = xsq[b * NPIX + n];
  double best = 1.0e300; int bi = 0;
  for (int kc = 0; kc < K; kc += KC) {
    double acc[KC];
    #pragma unroll
    for (int k = 0; k < KC; ++k) acc[k] = 0.0;
    for (int c0 = 0; c0 < CE; c0 += 16) {
      double xd[16];
      #pragma unroll
      for (int j = 0; j < 16; j += 4) {
        float4 v = *(const float4*)(xr + c0 + j);
        xd[j + 0] = (double)v.x; xd[j + 1] = (double)v.y;
        xd[j + 2] = (double)v.z; xd[j + 3] = (double)v.w;
      }
      for (int k = 0; k < KC; ++k) {
        const double* cp = cb + (long)(kc + k) * CE + c0;   // wave-uniform -> s_load
        #pragma unroll
        for (int j = 0; j < 16; ++j) acc[k] += xd[j] * cp[j];
      }
    }
    #pragma unroll
    for (int k = 0; k < KC; ++k) {
      double d = myxsq - 2.0 * acc[k] + csq_s[kc + k];
      if (d < best) { best = d; bi = kc + k; }
    }
  }
  float w = wts[b * NPIX + n];
  int a = (w > 0.f) ? bi : -1;
  assign[b * NPIX + n] = a;
  if (a >= 0) atomicAdd(&hist_s[a], 1);
  __syncthreads();
  if (t < K && hist_s[t] > 0) atomicAdd(&den[b * K + t], (double)hist_s[t]);
}

__global__ __launch_bounds__(256) void k_assign_dual(
    const float* __restrict__ X, const float* __restrict__ wfg, const float* __restrict__ wbg,
    const double* __restrict__ xsq,
    const double* __restrict__ cenF, const double* __restrict__ cenB,
    int* __restrict__ asgF, int* __restrict__ asgB,
    double* __restrict__ denF, double* __restrict__ denB) {
  __shared__ double csq_s[KBG];
  __shared__ int hist_s[KBG];
  if (blockIdx.z == 0)
    assign_impl<KFG, KFG>(X, wfg, xsq, cenF, asgF, denF, csq_s, hist_s);
  else
    assign_impl<KBG, 25>(X, wbg, xsq, cenB, asgB, denB, csq_s, hist_s);
}

// ---------------- kmeans accumulate (dual) ----------------
template <int K>
static __device__ __forceinline__ void reduce_impl(
    const float* __restrict__ X, const int* __restrict__ assign,
    double* __restrict__ num, int b, double* part, int* sa) {
  int c0 = blockIdx.y * 128;
  int n0 = blockIdx.x * 512;
  int t = threadIdx.x;
  for (int k = 0; k < K; ++k) part[k * 128 + t] = 0.0;
  for (int i = t; i < 512; i += 128) sa[i] = assign[b * NPIX + n0 + i];
  __syncthreads();
  for (int i = 0; i < 512; ++i) {
    int a = sa[i];
    if (a >= 0) {
      float x = X[((long)b * NPIX + n0 + i) * CE + c0 + t];
      part[a * 128 + t] += (double)x;
    }
  }
  __syncthreads();
  for (int k = 0; k < K; ++k) {
    double v = part[k * 128 + t];
    if (v != 0.0) atomicAdd(&num[((long)(b * K + k)) * CE + c0 + t], v);
  }
}

__global__ __launch_bounds__(128) void k_reduce_dual(
    const float* __restrict__ X, const int* __restrict__ asgF, const int* __restrict__ asgB,
    double* __restrict__ numF, double* __restrict__ numB) {
  __shared__ double part[KBG * 128];
  __shared__ int sa[512];
  int z = blockIdx.z;
  if (z < NB) reduce_impl<KFG>(X, asgF, numF, z, part, sa);
  else        reduce_impl<KBG>(X, asgB, numB, z - NB, part, sa);
}

__global__ void k_final_dual(
    const double* __restrict__ numF, const double* __restrict__ denF,
    const double* __restrict__ srcF, double* __restrict__ dstF, int naF,
    const double* __restrict__ numB, const double* __restrict__ denB,
    const double* __restrict__ srcB, double* __restrict__ dstB, int naB) {
  int i = blockIdx.x * 256 + threadIdx.x;
  if (i < naF) {
    double d = denF[i / CE];
    dstF[i] = (d > 0.0) ? numF[i] / fmax(d, 1e-6) : srcF[i];
  } else if (i - naF < naB) {
    int j = i - naF;
    double d = denB[j / CE];
    dstB[j] = (d > 0.0) ? numB[j] / fmax(d, 1e-6) : srcB[j];
  }
}

// ---------------- activation -> bf16 staging: out = bf16((A + A2) * rs) ----------------
__global__ void k_cvtA(const float* __restrict__ A, const float* __restrict__ A2,
                       const float* __restrict__ rs, unsigned short* __restrict__ out) {
  long i = (long)blockIdx.x * 256 + threadIdx.x;
  if (i >= (long)NB * NPIX * CE) return;
  float v = A[i];
  if (A2) v += A2[i];
  if (rs) v *= rs[i / CE];
  out[i] = f2bf(v);
}

// ---------------- weight transpose + cast ----------------
__global__ void k_cvtW(const float* __restrict__ W, unsigned short* __restrict__ Wt,
                       int K, int N, int Npad) {
  int i = blockIdx.x * 256 + threadIdx.x;
  if (i >= Npad * K) return;
  int n = i / K, k = i % K;
  Wt[i] = (n < N) ? f2bf(W[(long)k * N + n]) : (unsigned short)0;
}

// ---------------- bf16 MFMA GEMM: C = A @ Bt^T (+bias)(+relu) ----------------
__global__ __launch_bounds__(256) void k_gemm_bf(
    const unsigned short* __restrict__ A, const unsigned short* __restrict__ Bt,
    const float* __restrict__ bias, float* __restrict__ Cf, unsigned short* __restrict__ Cb,
    int M, int K, int N, int relu) {
  __shared__ unsigned short As[128 * 40];
  __shared__ unsigned short Bs[128 * 40];
  int m0 = blockIdx.y * 128, n0 = blockIdx.x * 128;
  int t = threadIdx.x;
  int w = t >> 6, l = t & 63;
  int wm = w >> 1, wn = w & 1;
  int half = l >> 4, lr = l & 15;
  float4v acc[4][4] = {};
  for (int k0 = 0; k0 < K; k0 += 32) {
    for (int c = t; c < 512; c += 256) {
      int r = c >> 2, part = c & 3;
      uint4 va = *(const uint4*)(A + (size_t)(m0 + r) * K + k0 + part * 8);
      *(uint4*)(&As[r * 40 + part * 8]) = va;
      uint4 vb = *(const uint4*)(Bt + (size_t)(n0 + r) * K + k0 + part * 8);
      *(uint4*)(&Bs[r * 40 + part * 8]) = vb;
    }
    __syncthreads();
    short8 af[4], bfr[4];
    #pragma unroll
    for (int am = 0; am < 4; ++am)
      af[am] = *(const short8*)(&As[(wm * 64 + am * 16 + lr) * 40 + half * 8]);
    #pragma unroll
    for (int bn = 0; bn < 4; ++bn)
      bfr[bn] = *(const short8*)(&Bs[(wn * 64 + bn * 16 + lr) * 40 + half * 8]);
    #pragma unroll
    for (int am = 0; am < 4; ++am)
      #pragma unroll
      for (int bn = 0; bn < 4; ++bn)
        acc[am][bn] = __builtin_amdgcn_mfma_f32_16x16x32_bf16(af[am], bfr[bn], acc[am][bn], 0, 0, 0);
    __syncthreads();
  }
  #pragma unroll
  for (int am = 0; am < 4; ++am) {
    #pragma unroll
    for (int bn = 0; bn < 4; ++bn) {
      int gc = n0 + wn * 64 + bn * 16 + lr;
      if (gc < N) {
        float bv = bias ? bias[gc] : 0.f;
        int gr0 = m0 + wm * 64 + am * 16 + half * 4;
        #pragma unroll
        for (int r = 0; r < 4; ++r) {
          float v = acc[am][bn][r] + bv;
          if (relu) v = fmaxf(v, 0.f);
          size_t oi = (size_t)(gr0 + r) * N + gc;
          if (Cf) Cf[oi] = v;
          else Cb[oi] = f2bf(v);
        }
      }
    }
  }
}

// ---------------- softmax over 9 points (bf16 in/out) ----------------
__global__ void k_softmax(unsigned short* __restrict__ aw) {
  long i = (long)blockIdx.x * 256 + threadIdx.x;
  if (i >= (long)NB * NPIX * NH) return;
  unsigned short* p = aw + i * NPTS;
  float f[NPTS];
  #pragma unroll
  for (int j = 0; j < NPTS; ++j) f[j] = bf2f(p[j]);
  float m = f[0];
  #pragma unroll
  for (int j = 1; j < NPTS; ++j) m = fmaxf(m, f[j]);
  float s = 0.f;
  #pragma unroll
  for (int j = 0; j < NPTS; ++j) { f[j] = expf(f[j] - m); s += f[j]; }
  float inv = 1.f / s;
  #pragma unroll
  for (int j = 0; j < NPTS; ++j) p[j] = f2bf(f[j] * inv);
}

// ---------------- bilinear sampler ----------------
__device__ __forceinline__ float sampleV(const float* __restrict__ vb, int xi, int yi, int c) {
  bool valid = (xi >= 0) & (xi < WDIM) & (yi >= 0) & (yi < HDIM);
  int xc = min(max(xi, 0), WDIM - 1), yc = min(max(yi, 0), HDIM - 1);
  float g = vb[(long)(yc * WDIM + xc) * CE + c];
  return valid ? g : 0.f;
}

__global__ void k_sample(const float* __restrict__ V, const unsigned short* __restrict__ OFF,
                         const unsigned short* __restrict__ AW, unsigned short* __restrict__ ATT) {
  long gid = (long)blockIdx.x * 256 + threadIdx.x;
  if (gid >= (long)NB * NPIX * CE) return;
  int c = (int)(gid % CE);
  long r = gid / CE;
  int n = (int)(r % NPIX);
  int b = (int)(r / NPIX);
  int h = c >> 5;
  int hh = n >> 6, ww = n & 63;
  const unsigned short* offp = OFF + ((long)(b * NPIX + n)) * 216 + h * 18;
  const unsigned short* awp  = AW  + ((long)(b * NPIX + n)) * 108 + h * 9;
  const float* vb = V + ((long)b * NPIX) * CE;
  float refx = ((float)ww + 0.5f) / (float)WDIM;
  float refy = ((float)hh + 0.5f) / (float)HDIM;
  float acc = 0.f;
  #pragma unroll
  for (int p = 0; p < NPTS; ++p) {
    float ox = bf2f(offp[p * 2 + 0]), oy = bf2f(offp[p * 2 + 1]);
    float lx = refx + ox / (float)WDIM;
    float ly = refy + oy / (float)HDIM;
    float xs = lx * (float)WDIM - 0.5f;
    float ys = ly * (float)HDIM - 0.5f;
    float x0f = floorf(xs), y0f = floorf(ys);
    float wx = xs - x0f, wy = ys - y0f;
    int x0 = (int)x0f, y0 = (int)y0f;
    float g00 = sampleV(vb, x0,     y0,     c);
    float g01 = sampleV(vb, x0 + 1, y0,     c);
    float g10 = sampleV(vb, x0,     y0 + 1, c);
    float g11 = sampleV(vb, x0 + 1, y0 + 1, c);
    float bil = g00 * (1.f - wx) * (1.f - wy) + g01 * wx * (1.f - wy)
              + g10 * (1.f - wx) * wy + g11 * wx * wy;
    acc += bf2f(awp[p]) * bil;
  }
  ATT[gid] = f2bf(acc);
}

// ---------------- LayerNorm(X + T) -> X ----------------
__global__ void k_ln(float* __restrict__ X, const float* __restrict__ T,
                     const float* __restrict__ g, const float* __restrict__ bb) {
  int row = blockIdx.x; int t = threadIdx.x;
  float* xr = X + (long)row * CE;
  const float* tr = T + (long)row * CE;
  float v[6]; float s = 0.f;
  #pragma unroll
  for (int i = 0; i < 6; ++i) { v[i] = xr[t + 64 * i] + tr[t + 64 * i]; s += v[i]; }
  #pragma unroll
  for (int o = 32; o > 0; o >>= 1) s += __shfl_down(s, o, 64);
  s = __shfl(s, 0, 64);
  float m = s / (float)CE;
  float var = 0.f;
  #pragma unroll
  for (int i = 0; i < 6; ++i) { float d = v[i] - m; var += d * d; }
  #pragma unroll
  for (int o = 32; o > 0; o >>= 1) var += __shfl_down(var, o, 64);
  var = __shfl(var, 0, 64);
  float rst = rsqrtf(var / (float)CE + 1e-5f);
  #pragma unroll
  for (int i = 0; i < 6; ++i) { int c = t + 64 * i; xr[c] = (v[i] - m) * rst * g[c] + bb[c]; }
}

// ---------------- assemble output ----------------
__global__ void k_out(const float* __restrict__ X, const double* __restrict__ fg,
                      const double* __restrict__ bg, float* __restrict__ out) {
  long i = (long)blockIdx.x * 256 + threadIdx.x;
  const long tot = (long)NB * (NPIX + KFG + KBG) * CE;
  if (i >= tot) return;
  int c = (int)(i % CE);
  long r = i / CE;
  int rr = (int)(r % (NPIX + KFG + KBG));
  int b = (int)(r / (NPIX + KFG + KBG));
  float v;
  if (rr < NPIX) v = X[((long)b * NPIX + rr) * CE + c];
  else if (rr < NPIX + KFG) v = (float)fg[((long)b * KFG + (rr - NPIX)) * CE + c];
  else v = (float)bg[((long)b * KBG + (rr - NPIX - KFG)) * CE + c];
  out[i] = v;
}

extern "C" void kernel_launch(void* const* d_in, const int* in_sizes, int n_in,
                              void* d_out, int out_size, void* d_ws, size_t ws_size,
                              hipStream_t stream) {
  (void)in_sizes; (void)n_in; (void)out_size; (void)ws_size;
  const float* s_x  = (const float*)d_in[0];
  const float* s_pm = (const float*)d_in[1];
  const float* s_sm = (const float*)d_in[2];
  const float* Wv   = (const float*)d_in[3];
  const float* bv   = (const float*)d_in[4];
  const float* Woff = (const float*)d_in[5];
  const float* boff = (const float*)d_in[6];
  const float* Wa   = (const float*)d_in[7];
  const float* ba   = (const float*)d_in[8];
  const float* Wout = (const float*)d_in[9];
  const float* bout = (const float*)d_in[10];
  const float* ln1g = (const float*)d_in[11];
  const float* ln1b = (const float*)d_in[12];
  const float* Wf1  = (const float*)d_in[13];
  const float* Wf2  = (const float*)d_in[14];
  const float* ln2g = (const float*)d_in[15];
  const float* ln2b = (const float*)d_in[16];
  float* out = (float*)d_out;
  char* pb = (char*)d_ws;

  const long BN  = (long)NB * NPIX;      // 16384
  const long BNC = BN * CE;              // 6291456

  float* X    = (float*)pb; pb += BNC * 4;
  float* POS  = (float*)pb; pb += BNC * 4;
  float* V    = (float*)pb; pb += BNC * 4;
  float* T2   = (float*)pb; pb += BNC * 4;
  unsigned short* QB   = (unsigned short*)pb; pb += BNC * 2;
  unsigned short* VBin = (unsigned short*)pb; pb += BNC * 2;
  unsigned short* T1b  = (unsigned short*)pb; pb += BNC * 2;
  unsigned short* Zbf  = QB;   // FFN hidden aliases QB+VBin+T1b
  unsigned short* XB   = (unsigned short*)pb; pb += BNC * 2;
  unsigned short* OFFb = (unsigned short*)pb; pb += BN * 216 * 2;
  unsigned short* AWb  = (unsigned short*)pb; pb += BN * 108 * 2;
  const int S_WV = 384 * 384, S_WOFF = 256 * 384, S_WA = 128 * 384,
            S_WOUT = 384 * 384, S_WF1 = 1152 * 384, S_WF2 = 384 * 1152;
  unsigned short* WT[NLAYERS][6];
  for (int l = 0; l < NLAYERS; ++l) {
    WT[l][0] = (unsigned short*)pb; pb += S_WV * 2;
    WT[l][1] = (unsigned short*)pb; pb += S_WOFF * 2;
    WT[l][2] = (unsigned short*)pb; pb += S_WA * 2;
    WT[l][3] = (unsigned short*)pb; pb += S_WOUT * 2;
    WT[l][4] = (unsigned short*)pb; pb += S_WF1 * 2;
    WT[l][5] = (unsigned short*)pb; pb += S_WF2 * 2;
  }
  float* padf = (float*)pb; pb += BN * 4;
  float* objf = (float*)pb; pb += BN * 4;
  float* notp = (float*)pb; pb += BN * 4;
  float* wfg  = (float*)pb; pb += BN * 4;
  float* wbg  = (float*)pb; pb += BN * 4;
  int*   asgF = (int*)pb; pb += BN * 4;
  int*   asgB = (int*)pb; pb += BN * 4;
  pb = (char*)(((size_t)pb + 7) & ~(size_t)7);
  double* xsq  = (double*)pb; pb += BN * 8;
  double* cFgA = (double*)pb; pb += (long)NB * KFG * CE * 8;
  double* cFgB = (double*)pb; pb += (long)NB * KFG * CE * 8;
  double* cBgA = (double*)pb; pb += (long)NB * KBG * CE * 8;
  double* cBgB = (double*)pb; pb += (long)NB * KBG * CE * 8;
  // contiguous zero region: numF, numB, denF, denB
  double* numF = (double*)pb; pb += (long)NB * KFG * CE * 8;
  double* numB = (double*)pb; pb += (long)NB * KBG * CE * 8;
  double* denF = (double*)pb; pb += NB * KFG * 8;
  double* denB = (double*)pb; pb += NB * KBG * 8;
  const long ZTOT = (long)NB * (KFG + KBG) * CE + NB * (KFG + KBG);

  int bn = (int)BN;
  int cvtBlocks = (int)((BNC + 255) / 256);

  k_masks<<<(bn + 255) / 256, 256, 0, stream>>>(s_pm, s_sm, padf, objf, notp, wfg, wbg);
  k_transpose<<<cvtBlocks, 256, 0, stream>>>(s_x, X);
  k_xsq<<<bn, 64, 0, stream>>>(X, xsq);
  k_pos<<<NB * HDIM, 256, 0, stream>>>(padf, POS);

  for (int l = 0; l < NLAYERS; ++l) {
    k_cvtW<<<(S_WV + 255) / 256, 256, 0, stream>>>(Wv + (long)l * CE * CE, WT[l][0], CE, 384, 384);
    k_cvtW<<<(S_WOFF + 255) / 256, 256, 0, stream>>>(Woff + (long)l * CE * 216, WT[l][1], CE, 216, 256);
    k_cvtW<<<(S_WA + 255) / 256, 256, 0, stream>>>(Wa + (long)l * CE * 108, WT[l][2], CE, 108, 128);
    k_cvtW<<<(S_WOUT + 255) / 256, 256, 0, stream>>>(Wout + (long)l * CE * CE, WT[l][3], CE, 384, 384);
    k_cvtW<<<(S_WF1 + 255) / 256, 256, 0, stream>>>(Wf1 + (long)l * CE * 1152, WT[l][4], CE, 1152, 1152);
    k_cvtW<<<(S_WF2 + 255) / 256, 256, 0, stream>>>(Wf2 + (long)l * 1152 * CE, WT[l][5], 1152, 384, 384);
  }

  // ---- kmeans (fg + bg fused per iteration) ----
  double *srcF = cFgA, *dstF = cFgB, *srcB = cBgA, *dstB = cBgB;
  k_kinit<<<NB, 256, 0, stream>>>(X, wfg, srcF, KFG);
  k_kinit<<<NB, 256, 0, stream>>>(X, wbg, srcB, KBG);
  int naF = NB * KFG * CE, naB = NB * KBG * CE;
  for (int it = 0; it < NITER; ++it) {
    k_zero_dual<<<(int)((ZTOT + 255) / 256), 256, 0, stream>>>(numF, ZTOT);
    k_assign_dual<<<dim3(NPIX / 256, NB, 2), 256, 0, stream>>>(
        X, wfg, wbg, xsq, srcF, srcB, asgF, asgB, denF, denB);
    k_reduce_dual<<<dim3(NPIX / 512, CE / 128, NB * 2), 128, 0, stream>>>(
        X, asgF, asgB, numF, numB);
    k_final_dual<<<(naF + naB + 255) / 256, 256, 0, stream>>>(
        numF, denF, srcF, dstF, naF, numB, denB, srcB, dstB, naB);
    double* tmp;
    tmp = srcF; srcF = dstF; dstF = tmp;
    tmp = srcB; srcB = dstB; dstB = tmp;
  }
  double* fgC = srcF; double* bgC = srcB;

  // ---- layers ----
  for (int l = 0; l < NLAYERS; ++l) {
    const float* bv_l   = bv   + l * CE;
    const float* boff_l = boff + l * 216;
    const float* ba_l   = ba   + l * 108;
    const float* bout_l = bout + l * CE;

    k_cvtA<<<cvtBlocks, 256, 0, stream>>>(X, POS, (const float*)nullptr, QB);
    k_cvtA<<<cvtBlocks, 256, 0, stream>>>(X, (const float*)nullptr, notp, VBin);
    k_gemm_bf<<<dim3(3, 128), 256, 0, stream>>>(VBin, WT[l][0], bv_l, V, (unsigned short*)nullptr,
                                                bn, CE, 384, 0);
    k_gemm_bf<<<dim3(2, 128), 256, 0, stream>>>(QB, WT[l][1], boff_l, (float*)nullptr, OFFb,
                                                bn, CE, 216, 0);
    k_gemm_bf<<<dim3(1, 128), 256, 0, stream>>>(QB, WT[l][2], ba_l, (float*)nullptr, AWb,
                                                bn, CE, 108, 0);
    k_softmax<<<(int)((BN * NH + 255) / 256), 256, 0, stream>>>(AWb);
    k_sample<<<cvtBlocks, 256, 0, stream>>>(V, OFFb, AWb, T1b);
    k_gemm_bf<<<dim3(3, 128), 256, 0, stream>>>(T1b, WT[l][3], bout_l, T2, (unsigned short*)nullptr,
                                                bn, CE, 384, 0);
    k_ln<<<bn, 64, 0, stream>>>(X, T2, ln1g + l * CE, ln1b + l * CE);
    k_cvtA<<<cvtBlocks, 256, 0, stream>>>(X, (const float*)nullptr, (const float*)nullptr, XB);
    k_gemm_bf<<<dim3(9, 128), 256, 0, stream>>>(XB, WT[l][4], (const float*)nullptr,
                                                (float*)nullptr, Zbf, bn, CE, 1152, 1);
    k_gemm_bf<<<dim3(3, 128), 256, 0, stream>>>(Zbf, WT[l][5], (const float*)nullptr,
                                                T2, (unsigned short*)nullptr, bn, 1152, 384, 0);
    k_ln<<<bn, 64, 0, stream>>>(X, T2, ln2g + l * CE, ln2b + l * CE);
  }

  k_out<<<(int)(((long)NB * (NPIX + KFG + KBG) * CE + 255) / 256), 256, 0, stream>>>(
      X, fgC, bgC, out);
}

// Round 6
// 2803.954 us; speedup vs baseline: 2.4091x; 2.4091x over previous
//
#include <hip/hip_runtime.h>
#include <hip/hip_bf16.h>
#include <math.h>

#define NB 4
#define CE 384
#define NH 12
#define DH 32
#define NPTS 9
#define NLAYERS 2
#define KFG 20
#define KBG 50
#define NITER 10
#define HDIM 64
#define WDIM 64
#define NPIX 4096
#define TWO_PI 6.283185307179586f

typedef __attribute__((ext_vector_type(8))) short short8;
typedef __attribute__((ext_vector_type(4))) float float4v;

static __device__ __forceinline__ unsigned short f2bf(float f) {
  __hip_bfloat16 h = __float2bfloat16(f);
  return *reinterpret_cast<unsigned short*>(&h);
}
static __device__ __forceinline__ float bf2f(unsigned short u) {
  unsigned x = ((unsigned)u) << 16;
  return __uint_as_float(x);
}

// ---------------- masks ----------------
__global__ void k_masks(const float* __restrict__ pm, const float* __restrict__ sm,
                        float* padf, float* objf, float* notp, float* wfg, float* wbg) {
  int i = blockIdx.x * 256 + threadIdx.x;
  if (i >= NB * NPIX) return;
  float p  = (pm[i] == 255.0f) ? 1.f : 0.f;
  float o  = (sm[i] == 1.0f) ? 1.f : 0.f;
  float np_ = 1.f - p;
  padf[i] = p; objf[i] = o; notp[i] = np_;
  wfg[i] = o * np_;
  wbg[i] = (1.f - o) * np_;
}

// ---------------- transpose s_x [B,C,N] -> X [B,N,C] ----------------
__global__ void k_transpose(const float* __restrict__ sx, float* __restrict__ X) {
  long i = (long)blockIdx.x * 256 + threadIdx.x;
  if (i >= (long)NB * NPIX * CE) return;
  int c = (int)(i % CE);
  long r = i / CE;
  int n = (int)(r % NPIX);
  int b = (int)(r / NPIX);
  X[i] = sx[((long)b * CE + c) * NPIX + n];
}

// ---------------- xsq (fp64) ----------------
__global__ void k_xsq(const float* __restrict__ X, double* __restrict__ xsq) {
  int row = blockIdx.x; int t = threadIdx.x;
  const float* xr = X + (long)row * CE;
  double s = 0.0;
  for (int i = t; i < CE; i += 64) { double v = (double)xr[i]; s += v * v; }
  #pragma unroll
  for (int o = 32; o > 0; o >>= 1) s += __shfl_down(s, o, 64);
  if (t == 0) xsq[row] = s;
}

// ---------------- sine positional encoding ----------------
__global__ void k_pos(const float* __restrict__ padf, float* __restrict__ POS) {
  int b = blockIdx.x / HDIM, hh = blockIdx.x % HDIM;
  __shared__ float xv[WDIM], yv[WDIM];
  int t = threadIdx.x;
  if (t < WDIM) {
    int w = t;
    float cum = 0.f, tot = 0.f;
    for (int h2 = 0; h2 < HDIM; ++h2) {
      float nm = 1.f - padf[b * NPIX + h2 * WDIM + w];
      tot += nm;
      if (h2 <= hh) cum += nm;
    }
    yv[w] = cum / (tot + 1e-6f) * TWO_PI;
    float rtot = 0.f, myc = 0.f;
    for (int w2 = 0; w2 < WDIM; ++w2) {
      float nm = 1.f - padf[b * NPIX + hh * WDIM + w2];
      rtot += nm;
      if (w2 <= w) myc += nm;
    }
    xv[w] = myc / (rtot + 1e-6f) * TWO_PI;
  }
  __syncthreads();
  const int nf = CE / 2;  // 192
  for (int i = t; i < WDIM * CE; i += 256) {
    int w = i / CE, c = i % CE;
    int tt = (c < nf) ? c : c - nf;
    float p = (c < nf) ? yv[w] : xv[w];
    float dt = powf(10000.0f, (float)(2 * (tt / 2)) / (float)nf);
    float v = p / dt;
    float r = (tt & 1) ? cosf(v) : sinf(v);
    POS[((long)(b * NPIX + hh * WDIM)) * CE + i] = r;
  }
}

// ---------------- kmeans init ----------------
__global__ void k_kinit(const float* __restrict__ X, const float* __restrict__ wts,
                        double* __restrict__ cen, int K) {
  int b = blockIdx.x;
  __shared__ int idx[KBG];
  if (threadIdx.x == 0) {
    int cnt = 0;
    for (int n = 0; n < NPIX && cnt < K; ++n) if (wts[b * NPIX + n] > 0.f) idx[cnt++] = n;
    for (int n = 0; n < NPIX && cnt < K; ++n) if (!(wts[b * NPIX + n] > 0.f)) idx[cnt++] = n;
  }
  __syncthreads();
  for (int i = threadIdx.x; i < K * CE; i += blockDim.x) {
    int k = i / CE, c = i % CE;
    cen[((long)b * K + k) * CE + c] = (double)X[((long)b * NPIX + idx[k]) * CE + c];
  }
}

__global__ void k_zero_dual(double* __restrict__ z, long total) {
  long i = (long)blockIdx.x * 256 + threadIdx.x;
  if (i < total) z[i] = 0.0;
}

// ---------------- kmeans distances: 10-center LDS tiles, 448 blocks (k-split) ----------------
// grid (BN/256, 7): z=0..1 -> fg k-tiles, z=2..6 -> bg k-tiles. Each thread = 1 pixel.
// Writes full distance d = xsq - 2*dot + csq into DF/DB (fp64), [n][k] layout.
__global__ __launch_bounds__(256) void k_dots(
    const float* __restrict__ X, const double* __restrict__ xsq,
    const double* __restrict__ cenF, const double* __restrict__ cenB,
    double* __restrict__ DF, double* __restrict__ DB) {
  __shared__ double ct[10][CE];
  __shared__ double csq_s[10];
  int z = blockIdx.y;
  int isBg = (z >= 2) ? 1 : 0;
  int k0 = isBg ? (z - 2) * 10 : z * 10;
  int t = threadIdx.x;
  int n = blockIdx.x * 256 + t;
  int b = blockIdx.x >> 4;                // NPIX/256 = 16 blocks per batch
  const double* cb = (isBg ? cenB + (long)b * KBG * CE
                           : cenF + (long)b * KFG * CE) + (long)k0 * CE;
  for (int i = t; i < 10 * CE; i += 256) ct[i / CE][i % CE] = cb[i];
  __syncthreads();
  if (t < 64) {
    for (int kk = 0; kk < 10; ++kk) {
      double s = 0.0;
      for (int c = t; c < CE; c += 64) { double v = ct[kk][c]; s += v * v; }
      #pragma unroll
      for (int o = 32; o > 0; o >>= 1) s += __shfl_down(s, o, 64);
      if (t == 0) csq_s[kk] = s;
    }
  }
  __syncthreads();
  const float* xr = X + (long)n * CE;
  double acc[10];
  #pragma unroll
  for (int k = 0; k < 10; ++k) acc[k] = 0.0;
  for (int c0 = 0; c0 < CE; c0 += 16) {
    double xd[16];
    #pragma unroll
    for (int j = 0; j < 16; j += 4) {
      float4 v = *(const float4*)(xr + c0 + j);
      xd[j + 0] = (double)v.x; xd[j + 1] = (double)v.y;
      xd[j + 2] = (double)v.z; xd[j + 3] = (double)v.w;
    }
    #pragma unroll
    for (int k = 0; k < 10; ++k) {
      #pragma unroll
      for (int j = 0; j < 16; ++j) acc[k] += xd[j] * ct[k][c0 + j];  // LDS broadcast
    }
  }
  double myxsq = xsq[n];
  double* Drow = (isBg ? DB + (long)n * KBG : DF + (long)n * KFG) + k0;
  #pragma unroll
  for (int k = 0; k < 10; ++k) Drow[k] = myxsq - 2.0 * acc[k] + csq_s[k];
}

// ---------------- kmeans argmin + histogram ----------------
// grid (BN/256, 2): z=0 fg, z=1 bg
__global__ __launch_bounds__(256) void k_argmin(
    const double* __restrict__ DF, const double* __restrict__ DB,
    const float* __restrict__ wfg, const float* __restrict__ wbg,
    int* __restrict__ asgF, int* __restrict__ asgB,
    double* __restrict__ denF, double* __restrict__ denB) {
  __shared__ int hist[KBG];
  int z = blockIdx.y;
  int K = z ? KBG : KFG;
  int t = threadIdx.x;
  int n = blockIdx.x * 256 + t;
  int b = blockIdx.x >> 4;
  if (t < K) hist[t] = 0;
  __syncthreads();
  const double* Drow = z ? (DB + (long)n * KBG) : (DF + (long)n * KFG);
  double best = 1.0e300; int bi = 0;
  for (int k = 0; k < K; ++k) {
    double d = Drow[k];
    if (d < best) { best = d; bi = k; }
  }
  float w = (z ? wbg : wfg)[n];
  int a = (w > 0.f) ? bi : -1;
  (z ? asgB : asgF)[n] = a;
  if (a >= 0) atomicAdd(&hist[a], 1);
  __syncthreads();
  double* den = z ? denB : denF;
  if (t < K && hist[t] > 0) atomicAdd(&den[b * K + t], (double)hist[t]);
}

// ---------------- kmeans accumulate (dual) ----------------
template <int K>
static __device__ __forceinline__ void reduce_impl(
    const float* __restrict__ X, const int* __restrict__ assign,
    double* __restrict__ num, int b, double* part, int* sa) {
  int c0 = blockIdx.y * 128;
  int n0 = blockIdx.x * 512;
  int t = threadIdx.x;
  for (int k = 0; k < K; ++k) part[k * 128 + t] = 0.0;
  for (int i = t; i < 512; i += 128) sa[i] = assign[b * NPIX + n0 + i];
  __syncthreads();
  for (int i = 0; i < 512; ++i) {
    int a = sa[i];
    if (a >= 0) {
      float x = X[((long)b * NPIX + n0 + i) * CE + c0 + t];
      part[a * 128 + t] += (double)x;
    }
  }
  __syncthreads();
  for (int k = 0; k < K; ++k) {
    double v = part[k * 128 + t];
    if (v != 0.0) atomicAdd(&num[((long)(b * K + k)) * CE + c0 + t], v);
  }
}

__global__ __launch_bounds__(128) void k_reduce_dual(
    const float* __restrict__ X, const int* __restrict__ asgF, const int* __restrict__ asgB,
    double* __restrict__ numF, double* __restrict__ numB) {
  __shared__ double part[KBG * 128];
  __shared__ int sa[512];
  int z = blockIdx.z;
  if (z < NB) reduce_impl<KFG>(X, asgF, numF, z, part, sa);
  else        reduce_impl<KBG>(X, asgB, numB, z - NB, part, sa);
}

__global__ void k_final_dual(
    const double* __restrict__ numF, const double* __restrict__ denF,
    const double* __restrict__ srcF, double* __restrict__ dstF, int naF,
    const double* __restrict__ numB, const double* __restrict__ denB,
    const double* __restrict__ srcB, double* __restrict__ dstB, int naB) {
  int i = blockIdx.x * 256 + threadIdx.x;
  if (i < naF) {
    double d = denF[i / CE];
    dstF[i] = (d > 0.0) ? numF[i] / fmax(d, 1e-6) : srcF[i];
  } else if (i - naF < naB) {
    int j = i - naF;
    double d = denB[j / CE];
    dstB[j] = (d > 0.0) ? numB[j] / fmax(d, 1e-6) : srcB[j];
  }
}

// ---------------- activation -> bf16 staging: out = bf16((A + A2) * rs) ----------------
__global__ void k_cvtA(const float* __restrict__ A, const float* __restrict__ A2,
                       const float* __restrict__ rs, unsigned short* __restrict__ out) {
  long i = (long)blockIdx.x * 256 + threadIdx.x;
  if (i >= (long)NB * NPIX * CE) return;
  float v = A[i];
  if (A2) v += A2[i];
  if (rs) v *= rs[i / CE];
  out[i] = f2bf(v);
}

// ---------------- weight transpose + cast ----------------
__global__ void k_cvtW(const float* __restrict__ W, unsigned short* __restrict__ Wt,
                       int K, int N, int Npad) {
  int i = blockIdx.x * 256 + threadIdx.x;
  if (i >= Npad * K) return;
  int n = i / K, k = i % K;
  Wt[i] = (n < N) ? f2bf(W[(long)k * N + n]) : (unsigned short)0;
}

// ---------------- bf16 MFMA GEMM: C = A @ Bt^T (+bias)(+relu) ----------------
__global__ __launch_bounds__(256) void k_gemm_bf(
    const unsigned short* __restrict__ A, const unsigned short* __restrict__ Bt,
    const float* __restrict__ bias, float* __restrict__ Cf, unsigned short* __restrict__ Cb,
    int M, int K, int N, int relu) {
  __shared__ unsigned short As[128 * 40];
  __shared__ unsigned short Bs[128 * 40];
  int m0 = blockIdx.y * 128, n0 = blockIdx.x * 128;
  int t = threadIdx.x;
  int w = t >> 6, l = t & 63;
  int wm = w >> 1, wn = w & 1;
  int half = l >> 4, lr = l & 15;
  float4v acc[4][4] = {};
  for (int k0 = 0; k0 < K; k0 += 32) {
    for (int c = t; c < 512; c += 256) {
      int r = c >> 2, part = c & 3;
      uint4 va = *(const uint4*)(A + (size_t)(m0 + r) * K + k0 + part * 8);
      *(uint4*)(&As[r * 40 + part * 8]) = va;
      uint4 vb = *(const uint4*)(Bt + (size_t)(n0 + r) * K + k0 + part * 8);
      *(uint4*)(&Bs[r * 40 + part * 8]) = vb;
    }
    __syncthreads();
    short8 af[4], bfr[4];
    #pragma unroll
    for (int am = 0; am < 4; ++am)
      af[am] = *(const short8*)(&As[(wm * 64 + am * 16 + lr) * 40 + half * 8]);
    #pragma unroll
    for (int bn = 0; bn < 4; ++bn)
      bfr[bn] = *(const short8*)(&Bs[(wn * 64 + bn * 16 + lr) * 40 + half * 8]);
    #pragma unroll
    for (int am = 0; am < 4; ++am)
      #pragma unroll
      for (int bn = 0; bn < 4; ++bn)
        acc[am][bn] = __builtin_amdgcn_mfma_f32_16x16x32_bf16(af[am], bfr[bn], acc[am][bn], 0, 0, 0);
    __syncthreads();
  }
  #pragma unroll
  for (int am = 0; am < 4; ++am) {
    #pragma unroll
    for (int bn = 0; bn < 4; ++bn) {
      int gc = n0 + wn * 64 + bn * 16 + lr;
      if (gc < N) {
        float bv = bias ? bias[gc] : 0.f;
        int gr0 = m0 + wm * 64 + am * 16 + half * 4;
        #pragma unroll
        for (int r = 0; r < 4; ++r) {
          float v = acc[am][bn][r] + bv;
          if (relu) v = fmaxf(v, 0.f);
          size_t oi = (size_t)(gr0 + r) * N + gc;
          if (Cf) Cf[oi] = v;
          else Cb[oi] = f2bf(v);
        }
      }
    }
  }
}

// ---------------- softmax over 9 points (bf16 in/out) ----------------
__global__ void k_softmax(unsigned short* __restrict__ aw) {
  long i = (long)blockIdx.x * 256 + threadIdx.x;
  if (i >= (long)NB * NPIX * NH) return;
  unsigned short* p = aw + i * NPTS;
  float f[NPTS];
  #pragma unroll
  for (int j = 0; j < NPTS; ++j) f[j] = bf2f(p[j]);
  float m = f[0];
  #pragma unroll
  for (int j = 1; j < NPTS; ++j) m = fmaxf(m, f[j]);
  float s = 0.f;
  #pragma unroll
  for (int j = 0; j < NPTS; ++j) { f[j] = expf(f[j] - m); s += f[j]; }
  float inv = 1.f / s;
  #pragma unroll
  for (int j = 0; j < NPTS; ++j) p[j] = f2bf(f[j] * inv);
}

// ---------------- bilinear sampler ----------------
__device__ __forceinline__ float sampleV(const float* __restrict__ vb, int xi, int yi, int c) {
  bool valid = (xi >= 0) & (xi < WDIM) & (yi >= 0) & (yi < HDIM);
  int xc = min(max(xi, 0), WDIM - 1), yc = min(max(yi, 0), HDIM - 1);
  float g = vb[(long)(yc * WDIM + xc) * CE + c];
  return valid ? g : 0.f;
}

__global__ void k_sample(const float* __restrict__ V, const unsigned short* __restrict__ OFF,
                         const unsigned short* __restrict__ AW, unsigned short* __restrict__ ATT) {
  long gid = (long)blockIdx.x * 256 + threadIdx.x;
  if (gid >= (long)NB * NPIX * CE) return;
  int c = (int)(gid % CE);
  long r = gid / CE;
  int n = (int)(r % NPIX);
  int b = (int)(r / NPIX);
  int h = c >> 5;
  int hh = n >> 6, ww = n & 63;
  const unsigned short* offp = OFF + ((long)(b * NPIX + n)) * 216 + h * 18;
  const unsigned short* awp  = AW  + ((long)(b * NPIX + n)) * 108 + h * 9;
  const float* vb = V + ((long)b * NPIX) * CE;
  float refx = ((float)ww + 0.5f) / (float)WDIM;
  float refy = ((float)hh + 0.5f) / (float)HDIM;
  float acc = 0.f;
  #pragma unroll
  for (int p = 0; p < NPTS; ++p) {
    float ox = bf2f(offp[p * 2 + 0]), oy = bf2f(offp[p * 2 + 1]);
    float lx = refx + ox / (float)WDIM;
    float ly = refy + oy / (float)HDIM;
    float xs = lx * (float)WDIM - 0.5f;
    float ys = ly * (float)HDIM - 0.5f;
    float x0f = floorf(xs), y0f = floorf(ys);
    float wx = xs - x0f, wy = ys - y0f;
    int x0 = (int)x0f, y0 = (int)y0f;
    float g00 = sampleV(vb, x0,     y0,     c);
    float g01 = sampleV(vb, x0 + 1, y0,     c);
    float g10 = sampleV(vb, x0,     y0 + 1, c);
    float g11 = sampleV(vb, x0 + 1, y0 + 1, c);
    float bil = g00 * (1.f - wx) * (1.f - wy) + g01 * wx * (1.f - wy)
              + g10 * (1.f - wx) * wy + g11 * wx * wy;
    acc += bf2f(awp[p]) * bil;
  }
  ATT[gid] = f2bf(acc);
}

// ---------------- LayerNorm(X + T) -> X ----------------
__global__ void k_ln(float* __restrict__ X, const float* __restrict__ T,
                     const float* __restrict__ g, const float* __restrict__ bb) {
  int row = blockIdx.x; int t = threadIdx.x;
  float* xr = X + (long)row * CE;
  const float* tr = T + (long)row * CE;
  float v[6]; float s = 0.f;
  #pragma unroll
  for (int i = 0; i < 6; ++i) { v[i] = xr[t + 64 * i] + tr[t + 64 * i]; s += v[i]; }
  #pragma unroll
  for (int o = 32; o > 0; o >>= 1) s += __shfl_down(s, o, 64);
  s = __shfl(s, 0, 64);
  float m = s / (float)CE;
  float var = 0.f;
  #pragma unroll
  for (int i = 0; i < 6; ++i) { float d = v[i] - m; var += d * d; }
  #pragma unroll
  for (int o = 32; o > 0; o >>= 1) var += __shfl_down(var, o, 64);
  var = __shfl(var, 0, 64);
  float rst = rsqrtf(var / (float)CE + 1e-5f);
  #pragma unroll
  for (int i = 0; i < 6; ++i) { int c = t + 64 * i; xr[c] = (v[i] - m) * rst * g[c] + bb[c]; }
}

// ---------------- assemble output ----------------
__global__ void k_out(const float* __restrict__ X, const double* __restrict__ fg,
                      const double* __restrict__ bg, float* __restrict__ out) {
  long i = (long)blockIdx.x * 256 + threadIdx.x;
  const long tot = (long)NB * (NPIX + KFG + KBG) * CE;
  if (i >= tot) return;
  int c = (int)(i % CE);
  long r = i / CE;
  int rr = (int)(r % (NPIX + KFG + KBG));
  int b = (int)(r / (NPIX + KFG + KBG));
  float v;
  if (rr < NPIX) v = X[((long)b * NPIX + rr) * CE + c];
  else if (rr < NPIX + KFG) v = (float)fg[((long)b * KFG + (rr - NPIX)) * CE + c];
  else v = (float)bg[((long)b * KBG + (rr - NPIX - KFG)) * CE + c];
  out[i] = v;
}

extern "C" void kernel_launch(void* const* d_in, const int* in_sizes, int n_in,
                              void* d_out, int out_size, void* d_ws, size_t ws_size,
                              hipStream_t stream) {
  (void)in_sizes; (void)n_in; (void)out_size; (void)ws_size;
  const float* s_x  = (const float*)d_in[0];
  const float* s_pm = (const float*)d_in[1];
  const float* s_sm = (const float*)d_in[2];
  const float* Wv   = (const float*)d_in[3];
  const float* bv   = (const float*)d_in[4];
  const float* Woff = (const float*)d_in[5];
  const float* boff = (const float*)d_in[6];
  const float* Wa   = (const float*)d_in[7];
  const float* ba   = (const float*)d_in[8];
  const float* Wout = (const float*)d_in[9];
  const float* bout = (const float*)d_in[10];
  const float* ln1g = (const float*)d_in[11];
  const float* ln1b = (const float*)d_in[12];
  const float* Wf1  = (const float*)d_in[13];
  const float* Wf2  = (const float*)d_in[14];
  const float* ln2g = (const float*)d_in[15];
  const float* ln2b = (const float*)d_in[16];
  float* out = (float*)d_out;
  char* pb = (char*)d_ws;

  const long BN  = (long)NB * NPIX;      // 16384
  const long BNC = BN * CE;              // 6291456

  float* X    = (float*)pb; pb += BNC * 4;
  float* POS  = (float*)pb; pb += BNC * 4;
  float* V    = (float*)pb; pb += BNC * 4;
  float* T2   = (float*)pb; pb += BNC * 4;
  unsigned short* QB   = (unsigned short*)pb; pb += BNC * 2;
  unsigned short* VBin = (unsigned short*)pb; pb += BNC * 2;
  unsigned short* T1b  = (unsigned short*)pb; pb += BNC * 2;
  unsigned short* Zbf  = QB;   // FFN hidden aliases QB+VBin+T1b
  unsigned short* XB   = (unsigned short*)pb; pb += BNC * 2;
  unsigned short* OFFb = (unsigned short*)pb; pb += BN * 216 * 2;
  unsigned short* AWb  = (unsigned short*)pb; pb += BN * 108 * 2;
  const int S_WV = 384 * 384, S_WOFF = 256 * 384, S_WA = 128 * 384,
            S_WOUT = 384 * 384, S_WF1 = 1152 * 384, S_WF2 = 384 * 1152;
  unsigned short* WT[NLAYERS][6];
  for (int l = 0; l < NLAYERS; ++l) {
    WT[l][0] = (unsigned short*)pb; pb += S_WV * 2;
    WT[l][1] = (unsigned short*)pb; pb += S_WOFF * 2;
    WT[l][2] = (unsigned short*)pb; pb += S_WA * 2;
    WT[l][3] = (unsigned short*)pb; pb += S_WOUT * 2;
    WT[l][4] = (unsigned short*)pb; pb += S_WF1 * 2;
    WT[l][5] = (unsigned short*)pb; pb += S_WF2 * 2;
  }
  float* padf = (float*)pb; pb += BN * 4;
  float* objf = (float*)pb; pb += BN * 4;
  float* notp = (float*)pb; pb += BN * 4;
  float* wfg  = (float*)pb; pb += BN * 4;
  float* wbg  = (float*)pb; pb += BN * 4;
  int*   asgF = (int*)pb; pb += BN * 4;
  int*   asgB = (int*)pb; pb += BN * 4;
  pb = (char*)(((size_t)pb + 7) & ~(size_t)7);
  double* xsq  = (double*)pb; pb += BN * 8;
  double* DF   = (double*)pb; pb += BN * KFG * 8;
  double* DB   = (double*)pb; pb += BN * KBG * 8;
  double* cFgA = (double*)pb; pb += (long)NB * KFG * CE * 8;
  double* cFgB = (double*)pb; pb += (long)NB * KFG * CE * 8;
  double* cBgA = (double*)pb; pb += (long)NB * KBG * CE * 8;
  double* cBgB = (double*)pb; pb += (long)NB * KBG * CE * 8;
  // contiguous zero region: numF, numB, denF, denB
  double* numF = (double*)pb; pb += (long)NB * KFG * CE * 8;
  double* numB = (double*)pb; pb += (long)NB * KBG * CE * 8;
  double* denF = (double*)pb; pb += NB * KFG * 8;
  double* denB = (double*)pb; pb += NB * KBG * 8;
  const long ZTOT = (long)NB * (KFG + KBG) * CE + NB * (KFG + KBG);

  int bn = (int)BN;
  int cvtBlocks = (int)((BNC + 255) / 256);

  k_masks<<<(bn + 255) / 256, 256, 0, stream>>>(s_pm, s_sm, padf, objf, notp, wfg, wbg);
  k_transpose<<<cvtBlocks, 256, 0, stream>>>(s_x, X);
  k_xsq<<<bn, 64, 0, stream>>>(X, xsq);
  k_pos<<<NB * HDIM, 256, 0, stream>>>(padf, POS);

  for (int l = 0; l < NLAYERS; ++l) {
    k_cvtW<<<(S_WV + 255) / 256, 256, 0, stream>>>(Wv + (long)l * CE * CE, WT[l][0], CE, 384, 384);
    k_cvtW<<<(S_WOFF + 255) / 256, 256, 0, stream>>>(Woff + (long)l * CE * 216, WT[l][1], CE, 216, 256);
    k_cvtW<<<(S_WA + 255) / 256, 256, 0, stream>>>(Wa + (long)l * CE * 108, WT[l][2], CE, 108, 128);
    k_cvtW<<<(S_WOUT + 255) / 256, 256, 0, stream>>>(Wout + (long)l * CE * CE, WT[l][3], CE, 384, 384);
    k_cvtW<<<(S_WF1 + 255) / 256, 256, 0, stream>>>(Wf1 + (long)l * CE * 1152, WT[l][4], CE, 1152, 1152);
    k_cvtW<<<(S_WF2 + 255) / 256, 256, 0, stream>>>(Wf2 + (long)l * 1152 * CE, WT[l][5], 1152, 384, 384);
  }

  // ---- kmeans (fg + bg, k-split dots -> argmin -> reduce -> final) ----
  double *srcF = cFgA, *dstF = cFgB, *srcB = cBgA, *dstB = cBgB;
  k_kinit<<<NB, 256, 0, stream>>>(X, wfg, srcF, KFG);
  k_kinit<<<NB, 256, 0, stream>>>(X, wbg, srcB, KBG);
  int naF = NB * KFG * CE, naB = NB * KBG * CE;
  for (int it = 0; it < NITER; ++it) {
    k_zero_dual<<<(int)((ZTOT + 255) / 256), 256, 0, stream>>>(numF, ZTOT);
    k_dots<<<dim3(bn / 256, 7), 256, 0, stream>>>(X, xsq, srcF, srcB, DF, DB);
    k_argmin<<<dim3(bn / 256, 2), 256, 0, stream>>>(DF, DB, wfg, wbg, asgF, asgB, denF, denB);
    k_reduce_dual<<<dim3(NPIX / 512, CE / 128, NB * 2), 128, 0, stream>>>(
        X, asgF, asgB, numF, numB);
    k_final_dual<<<(naF + naB + 255) / 256, 256, 0, stream>>>(
        numF, denF, srcF, dstF, naF, numB, denB, srcB, dstB, naB);
    double* tmp;
    tmp = srcF; srcF = dstF; dstF = tmp;
    tmp = srcB; srcB = dstB; dstB = tmp;
  }
  double* fgC = srcF; double* bgC = srcB;

  // ---- layers ----
  for (int l = 0; l < NLAYERS; ++l) {
    const float* bv_l   = bv   + l * CE;
    const float* boff_l = boff + l * 216;
    const float* ba_l   = ba   + l * 108;
    const float* bout_l = bout + l * CE;

    k_cvtA<<<cvtBlocks, 256, 0, stream>>>(X, POS, (const float*)nullptr, QB);
    k_cvtA<<<cvtBlocks, 256, 0, stream>>>(X, (const float*)nullptr, notp, VBin);
    k_gemm_bf<<<dim3(3, 128), 256, 0, stream>>>(VBin, WT[l][0], bv_l, V, (unsigned short*)nullptr,
                                                bn, CE, 384, 0);
    k_gemm_bf<<<dim3(2, 128), 256, 0, stream>>>(QB, WT[l][1], boff_l, (float*)nullptr, OFFb,
                                                bn, CE, 216, 0);
    k_gemm_bf<<<dim3(1, 128), 256, 0, stream>>>(QB, WT[l][2], ba_l, (float*)nullptr, AWb,
                                                bn, CE, 108, 0);
    k_softmax<<<(int)((BN * NH + 255) / 256), 256, 0, stream>>>(AWb);
    k_sample<<<cvtBlocks, 256, 0, stream>>>(V, OFFb, AWb, T1b);
    k_gemm_bf<<<dim3(3, 128), 256, 0, stream>>>(T1b, WT[l][3], bout_l, T2, (unsigned short*)nullptr,
                                                bn, CE, 384, 0);
    k_ln<<<bn, 64, 0, stream>>>(X, T2, ln1g + l * CE, ln1b + l * CE);
    k_cvtA<<<cvtBlocks, 256, 0, stream>>>(X, (const float*)nullptr, (const float*)nullptr, XB);
    k_gemm_bf<<<dim3(9, 128), 256, 0, stream>>>(XB, WT[l][4], (const float*)nullptr,
                                                (float*)nullptr, Zbf, bn, CE, 1152, 1);
    k_gemm_bf<<<dim3(3, 128), 256, 0, stream>>>(Zbf, WT[l][5], (const float*)nullptr,
                                                T2, (unsigned short*)nullptr, bn, 1152, 384, 0);
    k_ln<<<bn, 64, 0, stream>>>(X, T2, ln2g + l * CE, ln2b + l * CE);
  }

  k_out<<<(int)(((long)NB * (NPIX + KFG + KBG) * CE + 255) / 256), 256, 0, stream>>>(
      X, fgC, bgC, out);
}

// Round 7
// 1966.796 us; speedup vs baseline: 3.4346x; 1.4256x over previous
//
#include <hip/hip_runtime.h>
#include <hip/hip_bf16.h>
#include <math.h>

#define NB 4
#define CE 384
#define NH 12
#define DH 32
#define NPTS 9
#define NLAYERS 2
#define KFG 20
#define KBG 50
#define NITER 10
#define HDIM 64
#define WDIM 64
#define NPIX 4096
#define NCHUNK 32
#define TWO_PI 6.283185307179586f

typedef __attribute__((ext_vector_type(8))) short short8;
typedef __attribute__((ext_vector_type(4))) float float4v;

static __device__ __forceinline__ unsigned short f2bf(float f) {
  __hip_bfloat16 h = __float2bfloat16(f);
  return *reinterpret_cast<unsigned short*>(&h);
}
static __device__ __forceinline__ float bf2f(unsigned short u) {
  unsigned x = ((unsigned)u) << 16;
  return __uint_as_float(x);
}

// ---------------- masks ----------------
__global__ void k_masks(const float* __restrict__ pm, const float* __restrict__ sm,
                        float* padf, float* objf, float* notp, float* wfg, float* wbg) {
  int i = blockIdx.x * 256 + threadIdx.x;
  if (i >= NB * NPIX) return;
  float p  = (pm[i] == 255.0f) ? 1.f : 0.f;
  float o  = (sm[i] == 1.0f) ? 1.f : 0.f;
  float np_ = 1.f - p;
  padf[i] = p; objf[i] = o; notp[i] = np_;
  wfg[i] = o * np_;
  wbg[i] = (1.f - o) * np_;
}

// ---------------- transpose s_x [B,C,N] -> X [B,N,C] ----------------
__global__ void k_transpose(const float* __restrict__ sx, float* __restrict__ X) {
  long i = (long)blockIdx.x * 256 + threadIdx.x;
  if (i >= (long)NB * NPIX * CE) return;
  int c = (int)(i % CE);
  long r = i / CE;
  int n = (int)(r % NPIX);
  int b = (int)(r / NPIX);
  X[i] = sx[((long)b * CE + c) * NPIX + n];
}

// ---------------- xsq (fp64) ----------------
__global__ void k_xsq(const float* __restrict__ X, double* __restrict__ xsq) {
  int row = blockIdx.x; int t = threadIdx.x;
  const float* xr = X + (long)row * CE;
  double s = 0.0;
  for (int i = t; i < CE; i += 64) { double v = (double)xr[i]; s += v * v; }
  #pragma unroll
  for (int o = 32; o > 0; o >>= 1) s += __shfl_down(s, o, 64);
  if (t == 0) xsq[row] = s;
}

// ---------------- sine positional encoding ----------------
__global__ void k_pos(const float* __restrict__ padf, float* __restrict__ POS) {
  int b = blockIdx.x / HDIM, hh = blockIdx.x % HDIM;
  __shared__ float xv[WDIM], yv[WDIM];
  int t = threadIdx.x;
  if (t < WDIM) {
    int w = t;
    float cum = 0.f, tot = 0.f;
    for (int h2 = 0; h2 < HDIM; ++h2) {
      float nm = 1.f - padf[b * NPIX + h2 * WDIM + w];
      tot += nm;
      if (h2 <= hh) cum += nm;
    }
    yv[w] = cum / (tot + 1e-6f) * TWO_PI;
    float rtot = 0.f, myc = 0.f;
    for (int w2 = 0; w2 < WDIM; ++w2) {
      float nm = 1.f - padf[b * NPIX + hh * WDIM + w2];
      rtot += nm;
      if (w2 <= w) myc += nm;
    }
    xv[w] = myc / (rtot + 1e-6f) * TWO_PI;
  }
  __syncthreads();
  const int nf = CE / 2;  // 192
  for (int i = t; i < WDIM * CE; i += 256) {
    int w = i / CE, c = i % CE;
    int tt = (c < nf) ? c : c - nf;
    float p = (c < nf) ? yv[w] : xv[w];
    float dt = powf(10000.0f, (float)(2 * (tt / 2)) / (float)nf);
    float v = p / dt;
    float r = (tt & 1) ? cosf(v) : sinf(v);
    POS[((long)(b * NPIX + hh * WDIM)) * CE + i] = r;
  }
}

// ---------------- kmeans init ----------------
__global__ void k_kinit(const float* __restrict__ X, const float* __restrict__ wts,
                        double* __restrict__ cen, int K) {
  int b = blockIdx.x;
  __shared__ int idx[KBG];
  if (threadIdx.x == 0) {
    int cnt = 0;
    for (int n = 0; n < NPIX && cnt < K; ++n) if (wts[b * NPIX + n] > 0.f) idx[cnt++] = n;
    for (int n = 0; n < NPIX && cnt < K; ++n) if (!(wts[b * NPIX + n] > 0.f)) idx[cnt++] = n;
  }
  __syncthreads();
  for (int i = threadIdx.x; i < K * CE; i += blockDim.x) {
    int k = i / CE, c = i % CE;
    cen[((long)b * K + k) * CE + c] = (double)X[((long)b * NPIX + idx[k]) * CE + c];
  }
}

__global__ void k_zero_den(double* __restrict__ z, int total) {
  int i = blockIdx.x * 256 + threadIdx.x;
  if (i < total) z[i] = 0.0;
}

// ---------------- kmeans distances: 10-center LDS tiles, 448 blocks (k-split) ----------------
__global__ __launch_bounds__(256) void k_dots(
    const float* __restrict__ X, const double* __restrict__ xsq,
    const double* __restrict__ cenF, const double* __restrict__ cenB,
    double* __restrict__ DF, double* __restrict__ DB) {
  __shared__ double ct[10][CE];
  __shared__ double csq_s[10];
  int z = blockIdx.y;
  int isBg = (z >= 2) ? 1 : 0;
  int k0 = isBg ? (z - 2) * 10 : z * 10;
  int t = threadIdx.x;
  int n = blockIdx.x * 256 + t;
  int b = blockIdx.x >> 4;                // NPIX/256 = 16 blocks per batch
  const double* cb = (isBg ? cenB + (long)b * KBG * CE
                           : cenF + (long)b * KFG * CE) + (long)k0 * CE;
  for (int i = t; i < 10 * CE; i += 256) ct[i / CE][i % CE] = cb[i];
  __syncthreads();
  if (t < 64) {
    for (int kk = 0; kk < 10; ++kk) {
      double s = 0.0;
      for (int c = t; c < CE; c += 64) { double v = ct[kk][c]; s += v * v; }
      #pragma unroll
      for (int o = 32; o > 0; o >>= 1) s += __shfl_down(s, o, 64);
      if (t == 0) csq_s[kk] = s;
    }
  }
  __syncthreads();
  const float* xr = X + (long)n * CE;
  double acc[10];
  #pragma unroll
  for (int k = 0; k < 10; ++k) acc[k] = 0.0;
  for (int c0 = 0; c0 < CE; c0 += 16) {
    double xd[16];
    #pragma unroll
    for (int j = 0; j < 16; j += 4) {
      float4 v = *(const float4*)(xr + c0 + j);
      xd[j + 0] = (double)v.x; xd[j + 1] = (double)v.y;
      xd[j + 2] = (double)v.z; xd[j + 3] = (double)v.w;
    }
    #pragma unroll
    for (int k = 0; k < 10; ++k) {
      #pragma unroll
      for (int j = 0; j < 16; ++j) acc[k] += xd[j] * ct[k][c0 + j];  // LDS broadcast
    }
  }
  double myxsq = xsq[n];
  double* Drow = (isBg ? DB + (long)n * KBG : DF + (long)n * KFG) + k0;
  #pragma unroll
  for (int k = 0; k < 10; ++k) Drow[k] = myxsq - 2.0 * acc[k] + csq_s[k];
}

// ---------------- kmeans argmin + histogram ----------------
__global__ __launch_bounds__(256) void k_argmin(
    const double* __restrict__ DF, const double* __restrict__ DB,
    const float* __restrict__ wfg, const float* __restrict__ wbg,
    int* __restrict__ asgF, int* __restrict__ asgB,
    double* __restrict__ denF, double* __restrict__ denB) {
  __shared__ int hist[KBG];
  int z = blockIdx.y;
  int K = z ? KBG : KFG;
  int t = threadIdx.x;
  int n = blockIdx.x * 256 + t;
  int b = blockIdx.x >> 4;
  if (t < K) hist[t] = 0;
  __syncthreads();
  const double* Drow = z ? (DB + (long)n * KBG) : (DF + (long)n * KFG);
  double best = 1.0e300; int bi = 0;
  for (int k = 0; k < K; ++k) {
    double d = Drow[k];
    if (d < best) { best = d; bi = k; }
  }
  float w = (z ? wbg : wfg)[n];
  int a = (w > 0.f) ? bi : -1;
  (z ? asgB : asgF)[n] = a;
  if (a >= 0) atomicAdd(&hist[a], 1);
  __syncthreads();
  double* den = z ? denB : denF;
  if (t < K && hist[t] > 0) atomicAdd(&den[b * K + t], (double)hist[t]);
}

// ---------------- kmeans reduce stage 1: per-chunk partials, no atomics ----------------
// grid (NPIX/128 = NCHUNK, CE/128 = 3, NB*2), block 128
template <int K>
static __device__ __forceinline__ void reduce1_impl(
    const float* __restrict__ X, const int* __restrict__ assign,
    double* __restrict__ pout, int b, double* part, int* sa) {
  int chunk = blockIdx.x;
  int c0 = blockIdx.y * 128;
  int n0 = chunk * 128;
  int t = threadIdx.x;
  for (int k = 0; k < K; ++k) part[k * 128 + t] = 0.0;
  sa[t] = assign[b * NPIX + n0 + t];
  __syncthreads();
  for (int i = 0; i < 128; ++i) {
    int a = sa[i];
    if (a >= 0) {
      float x = X[((long)b * NPIX + n0 + i) * CE + c0 + t];
      part[a * 128 + t] += (double)x;
    }
  }
  __syncthreads();
  for (int k = 0; k < K; ++k)
    pout[(((long)chunk * NB + b) * K + k) * CE + c0 + t] = part[k * 128 + t];
}

__global__ __launch_bounds__(128) void k_reduce1(
    const float* __restrict__ X, const int* __restrict__ asgF, const int* __restrict__ asgB,
    double* __restrict__ PF, double* __restrict__ PB) {
  __shared__ double part[KBG * 128];
  __shared__ int sa[128];
  int z = blockIdx.z;
  if (z < NB) reduce1_impl<KFG>(X, asgF, PF, z, part, sa);
  else        reduce1_impl<KBG>(X, asgB, PB, z - NB, part, sa);
}

// ---------------- kmeans reduce stage 2 + center update (fused final) ----------------
__global__ void k_reduce2f(
    const double* __restrict__ PF, const double* __restrict__ denF,
    const double* __restrict__ srcF, double* __restrict__ dstF, int naF,
    const double* __restrict__ PB, const double* __restrict__ denB,
    const double* __restrict__ srcB, double* __restrict__ dstB, int naB) {
  int i = blockIdx.x * 256 + threadIdx.x;
  const double* P; const double* den; const double* src; double* dst; int K; int idx;
  if (i < naF) { P = PF; den = denF; src = srcF; dst = dstF; K = KFG; idx = i; }
  else if (i - naF < naB) { P = PB; den = denB; src = srcB; dst = dstB; K = KBG; idx = i - naF; }
  else return;
  long stride = (long)NB * K * CE;
  double s = 0.0;
  for (int ch = 0; ch < NCHUNK; ++ch) s += P[(long)ch * stride + idx];
  double d = den[idx / CE];
  dst[idx] = (d > 0.0) ? s / fmax(d, 1e-6) : src[idx];
}

// ---------------- activation -> bf16 staging: out = bf16((A + A2) * rs) ----------------
__global__ void k_cvtA(const float* __restrict__ A, const float* __restrict__ A2,
                       const float* __restrict__ rs, unsigned short* __restrict__ out) {
  long i = (long)blockIdx.x * 256 + threadIdx.x;
  if (i >= (long)NB * NPIX * CE) return;
  float v = A[i];
  if (A2) v += A2[i];
  if (rs) v *= rs[i / CE];
  out[i] = f2bf(v);
}

// ---------------- weight transpose + cast ----------------
__global__ void k_cvtW(const float* __restrict__ W, unsigned short* __restrict__ Wt,
                       int K, int N, int Npad) {
  int i = blockIdx.x * 256 + threadIdx.x;
  if (i >= Npad * K) return;
  int n = i / K, k = i % K;
  Wt[i] = (n < N) ? f2bf(W[(long)k * N + n]) : (unsigned short)0;
}

// ---------------- bf16 MFMA GEMM: C = A @ Bt^T (+bias)(+relu) ----------------
__global__ __launch_bounds__(256) void k_gemm_bf(
    const unsigned short* __restrict__ A, const unsigned short* __restrict__ Bt,
    const float* __restrict__ bias, float* __restrict__ Cf, unsigned short* __restrict__ Cb,
    int M, int K, int N, int relu) {
  __shared__ unsigned short As[128 * 40];
  __shared__ unsigned short Bs[128 * 40];
  int m0 = blockIdx.y * 128, n0 = blockIdx.x * 128;
  int t = threadIdx.x;
  int w = t >> 6, l = t & 63;
  int wm = w >> 1, wn = w & 1;
  int half = l >> 4, lr = l & 15;
  float4v acc[4][4] = {};
  for (int k0 = 0; k0 < K; k0 += 32) {
    for (int c = t; c < 512; c += 256) {
      int r = c >> 2, part = c & 3;
      uint4 va = *(const uint4*)(A + (size_t)(m0 + r) * K + k0 + part * 8);
      *(uint4*)(&As[r * 40 + part * 8]) = va;
      uint4 vb = *(const uint4*)(Bt + (size_t)(n0 + r) * K + k0 + part * 8);
      *(uint4*)(&Bs[r * 40 + part * 8]) = vb;
    }
    __syncthreads();
    short8 af[4], bfr[4];
    #pragma unroll
    for (int am = 0; am < 4; ++am)
      af[am] = *(const short8*)(&As[(wm * 64 + am * 16 + lr) * 40 + half * 8]);
    #pragma unroll
    for (int bn = 0; bn < 4; ++bn)
      bfr[bn] = *(const short8*)(&Bs[(wn * 64 + bn * 16 + lr) * 40 + half * 8]);
    #pragma unroll
    for (int am = 0; am < 4; ++am)
      #pragma unroll
      for (int bn = 0; bn < 4; ++bn)
        acc[am][bn] = __builtin_amdgcn_mfma_f32_16x16x32_bf16(af[am], bfr[bn], acc[am][bn], 0, 0, 0);
    __syncthreads();
  }
  #pragma unroll
  for (int am = 0; am < 4; ++am) {
    #pragma unroll
    for (int bn = 0; bn < 4; ++bn) {
      int gc = n0 + wn * 64 + bn * 16 + lr;
      if (gc < N) {
        float bv = bias ? bias[gc] : 0.f;
        int gr0 = m0 + wm * 64 + am * 16 + half * 4;
        #pragma unroll
        for (int r = 0; r < 4; ++r) {
          float v = acc[am][bn][r] + bv;
          if (relu) v = fmaxf(v, 0.f);
          size_t oi = (size_t)(gr0 + r) * N + gc;
          if (Cf) Cf[oi] = v;
          else Cb[oi] = f2bf(v);
        }
      }
    }
  }
}

// ---------------- softmax over 9 points (bf16 in/out) ----------------
__global__ void k_softmax(unsigned short* __restrict__ aw) {
  long i = (long)blockIdx.x * 256 + threadIdx.x;
  if (i >= (long)NB * NPIX * NH) return;
  unsigned short* p = aw + i * NPTS;
  float f[NPTS];
  #pragma unroll
  for (int j = 0; j < NPTS; ++j) f[j] = bf2f(p[j]);
  float m = f[0];
  #pragma unroll
  for (int j = 1; j < NPTS; ++j) m = fmaxf(m, f[j]);
  float s = 0.f;
  #pragma unroll
  for (int j = 0; j < NPTS; ++j) { f[j] = expf(f[j] - m); s += f[j]; }
  float inv = 1.f / s;
  #pragma unroll
  for (int j = 0; j < NPTS; ++j) p[j] = f2bf(f[j] * inv);
}

// ---------------- bilinear sampler ----------------
__device__ __forceinline__ float sampleV(const float* __restrict__ vb, int xi, int yi, int c) {
  bool valid = (xi >= 0) & (xi < WDIM) & (yi >= 0) & (yi < HDIM);
  int xc = min(max(xi, 0), WDIM - 1), yc = min(max(yi, 0), HDIM - 1);
  float g = vb[(long)(yc * WDIM + xc) * CE + c];
  return valid ? g : 0.f;
}

__global__ void k_sample(const float* __restrict__ V, const unsigned short* __restrict__ OFF,
                         const unsigned short* __restrict__ AW, unsigned short* __restrict__ ATT) {
  long gid = (long)blockIdx.x * 256 + threadIdx.x;
  if (gid >= (long)NB * NPIX * CE) return;
  int c = (int)(gid % CE);
  long r = gid / CE;
  int n = (int)(r % NPIX);
  int b = (int)(r / NPIX);
  int h = c >> 5;
  int hh = n >> 6, ww = n & 63;
  const unsigned short* offp = OFF + ((long)(b * NPIX + n)) * 216 + h * 18;
  const unsigned short* awp  = AW  + ((long)(b * NPIX + n)) * 108 + h * 9;
  const float* vb = V + ((long)b * NPIX) * CE;
  float refx = ((float)ww + 0.5f) / (float)WDIM;
  float refy = ((float)hh + 0.5f) / (float)HDIM;
  float acc = 0.f;
  #pragma unroll
  for (int p = 0; p < NPTS; ++p) {
    float ox = bf2f(offp[p * 2 + 0]), oy = bf2f(offp[p * 2 + 1]);
    float lx = refx + ox / (float)WDIM;
    float ly = refy + oy / (float)HDIM;
    float xs = lx * (float)WDIM - 0.5f;
    float ys = ly * (float)HDIM - 0.5f;
    float x0f = floorf(xs), y0f = floorf(ys);
    float wx = xs - x0f, wy = ys - y0f;
    int x0 = (int)x0f, y0 = (int)y0f;
    float g00 = sampleV(vb, x0,     y0,     c);
    float g01 = sampleV(vb, x0 + 1, y0,     c);
    float g10 = sampleV(vb, x0,     y0 + 1, c);
    float g11 = sampleV(vb, x0 + 1, y0 + 1, c);
    float bil = g00 * (1.f - wx) * (1.f - wy) + g01 * wx * (1.f - wy)
              + g10 * (1.f - wx) * wy + g11 * wx * wy;
    acc += bf2f(awp[p]) * bil;
  }
  ATT[gid] = f2bf(acc);
}

// ---------------- LayerNorm(X + T) -> X ----------------
__global__ void k_ln(float* __restrict__ X, const float* __restrict__ T,
                     const float* __restrict__ g, const float* __restrict__ bb) {
  int row = blockIdx.x; int t = threadIdx.x;
  float* xr = X + (long)row * CE;
  const float* tr = T + (long)row * CE;
  float v[6]; float s = 0.f;
  #pragma unroll
  for (int i = 0; i < 6; ++i) { v[i] = xr[t + 64 * i] + tr[t + 64 * i]; s += v[i]; }
  #pragma unroll
  for (int o = 32; o > 0; o >>= 1) s += __shfl_down(s, o, 64);
  s = __shfl(s, 0, 64);
  float m = s / (float)CE;
  float var = 0.f;
  #pragma unroll
  for (int i = 0; i < 6; ++i) { float d = v[i] - m; var += d * d; }
  #pragma unroll
  for (int o = 32; o > 0; o >>= 1) var += __shfl_down(var, o, 64);
  var = __shfl(var, 0, 64);
  float rst = rsqrtf(var / (float)CE + 1e-5f);
  #pragma unroll
  for (int i = 0; i < 6; ++i) { int c = t + 64 * i; xr[c] = (v[i] - m) * rst * g[c] + bb[c]; }
}

// ---------------- assemble output ----------------
__global__ void k_out(const float* __restrict__ X, const double* __restrict__ fg,
                      const double* __restrict__ bg, float* __restrict__ out) {
  long i = (long)blockIdx.x * 256 + threadIdx.x;
  const long tot = (long)NB * (NPIX + KFG + KBG) * CE;
  if (i >= tot) return;
  int c = (int)(i % CE);
  long r = i / CE;
  int rr = (int)(r % (NPIX + KFG + KBG));
  int b = (int)(r / (NPIX + KFG + KBG));
  float v;
  if (rr < NPIX) v = X[((long)b * NPIX + rr) * CE + c];
  else if (rr < NPIX + KFG) v = (float)fg[((long)b * KFG + (rr - NPIX)) * CE + c];
  else v = (float)bg[((long)b * KBG + (rr - NPIX - KFG)) * CE + c];
  out[i] = v;
}

extern "C" void kernel_launch(void* const* d_in, const int* in_sizes, int n_in,
                              void* d_out, int out_size, void* d_ws, size_t ws_size,
                              hipStream_t stream) {
  (void)in_sizes; (void)n_in; (void)out_size; (void)ws_size;
  const float* s_x  = (const float*)d_in[0];
  const float* s_pm = (const float*)d_in[1];
  const float* s_sm = (const float*)d_in[2];
  const float* Wv   = (const float*)d_in[3];
  const float* bv   = (const float*)d_in[4];
  const float* Woff = (const float*)d_in[5];
  const float* boff = (const float*)d_in[6];
  const float* Wa   = (const float*)d_in[7];
  const float* ba   = (const float*)d_in[8];
  const float* Wout = (const float*)d_in[9];
  const float* bout = (const float*)d_in[10];
  const float* ln1g = (const float*)d_in[11];
  const float* ln1b = (const float*)d_in[12];
  const float* Wf1  = (const float*)d_in[13];
  const float* Wf2  = (const float*)d_in[14];
  const float* ln2g = (const float*)d_in[15];
  const float* ln2b = (const float*)d_in[16];
  float* out = (float*)d_out;
  char* pb = (char*)d_ws;

  const long BN  = (long)NB * NPIX;      // 16384
  const long BNC = BN * CE;              // 6291456

  float* X    = (float*)pb; pb += BNC * 4;
  float* POS  = (float*)pb; pb += BNC * 4;
  float* V    = (float*)pb; pb += BNC * 4;
  float* T2   = (float*)pb; pb += BNC * 4;
  // k-means chunk partials alias V/T2 (dead until layers start)
  double* PF  = (double*)V;    // needs NCHUNK*NB*KFG*CE*8 = 7.9 MB  (< 24 MB)
  double* PB  = (double*)T2;   // needs NCHUNK*NB*KBG*CE*8 = 19.7 MB (< 24 MB)
  unsigned short* QB   = (unsigned short*)pb; pb += BNC * 2;
  unsigned short* VBin = (unsigned short*)pb; pb += BNC * 2;
  unsigned short* T1b  = (unsigned short*)pb; pb += BNC * 2;
  unsigned short* Zbf  = QB;   // FFN hidden aliases QB+VBin+T1b
  unsigned short* XB   = (unsigned short*)pb; pb += BNC * 2;
  unsigned short* OFFb = (unsigned short*)pb; pb += BN * 216 * 2;
  unsigned short* AWb  = (unsigned short*)pb; pb += BN * 108 * 2;
  const int S_WV = 384 * 384, S_WOFF = 256 * 384, S_WA = 128 * 384,
            S_WOUT = 384 * 384, S_WF1 = 1152 * 384, S_WF2 = 384 * 1152;
  unsigned short* WT[NLAYERS][6];
  for (int l = 0; l < NLAYERS; ++l) {
    WT[l][0] = (unsigned short*)pb; pb += S_WV * 2;
    WT[l][1] = (unsigned short*)pb; pb += S_WOFF * 2;
    WT[l][2] = (unsigned short*)pb; pb += S_WA * 2;
    WT[l][3] = (unsigned short*)pb; pb += S_WOUT * 2;
    WT[l][4] = (unsigned short*)pb; pb += S_WF1 * 2;
    WT[l][5] = (unsigned short*)pb; pb += S_WF2 * 2;
  }
  float* padf = (float*)pb; pb += BN * 4;
  float* objf = (float*)pb; pb += BN * 4;
  float* notp = (float*)pb; pb += BN * 4;
  float* wfg  = (float*)pb; pb += BN * 4;
  float* wbg  = (float*)pb; pb += BN * 4;
  int*   asgF = (int*)pb; pb += BN * 4;
  int*   asgB = (int*)pb; pb += BN * 4;
  pb = (char*)(((size_t)pb + 7) & ~(size_t)7);
  double* xsq  = (double*)pb; pb += BN * 8;
  double* DF   = (double*)pb; pb += BN * KFG * 8;
  double* DB   = (double*)pb; pb += BN * KBG * 8;
  double* cFgA = (double*)pb; pb += (long)NB * KFG * CE * 8;
  double* cFgB = (double*)pb; pb += (long)NB * KFG * CE * 8;
  double* cBgA = (double*)pb; pb += (long)NB * KBG * CE * 8;
  double* cBgB = (double*)pb; pb += (long)NB * KBG * CE * 8;
  double* denF = (double*)pb; pb += NB * KFG * 8;
  double* denB = (double*)pb; pb += NB * KBG * 8;
  const int DEN_TOT = NB * (KFG + KBG);   // denF,denB contiguous

  int bn = (int)BN;
  int cvtBlocks = (int)((BNC + 255) / 256);

  k_masks<<<(bn + 255) / 256, 256, 0, stream>>>(s_pm, s_sm, padf, objf, notp, wfg, wbg);
  k_transpose<<<cvtBlocks, 256, 0, stream>>>(s_x, X);
  k_xsq<<<bn, 64, 0, stream>>>(X, xsq);
  k_pos<<<NB * HDIM, 256, 0, stream>>>(padf, POS);

  for (int l = 0; l < NLAYERS; ++l) {
    k_cvtW<<<(S_WV + 255) / 256, 256, 0, stream>>>(Wv + (long)l * CE * CE, WT[l][0], CE, 384, 384);
    k_cvtW<<<(S_WOFF + 255) / 256, 256, 0, stream>>>(Woff + (long)l * CE * 216, WT[l][1], CE, 216, 256);
    k_cvtW<<<(S_WA + 255) / 256, 256, 0, stream>>>(Wa + (long)l * CE * 108, WT[l][2], CE, 108, 128);
    k_cvtW<<<(S_WOUT + 255) / 256, 256, 0, stream>>>(Wout + (long)l * CE * CE, WT[l][3], CE, 384, 384);
    k_cvtW<<<(S_WF1 + 255) / 256, 256, 0, stream>>>(Wf1 + (long)l * CE * 1152, WT[l][4], CE, 1152, 1152);
    k_cvtW<<<(S_WF2 + 255) / 256, 256, 0, stream>>>(Wf2 + (long)l * 1152 * CE, WT[l][5], 1152, 384, 384);
  }

  // ---- kmeans (fg + bg: dots -> argmin -> reduce1 -> reduce2+final) ----
  double *srcF = cFgA, *dstF = cFgB, *srcB = cBgA, *dstB = cBgB;
  k_kinit<<<NB, 256, 0, stream>>>(X, wfg, srcF, KFG);
  k_kinit<<<NB, 256, 0, stream>>>(X, wbg, srcB, KBG);
  int naF = NB * KFG * CE, naB = NB * KBG * CE;
  for (int it = 0; it < NITER; ++it) {
    k_zero_den<<<2, 256, 0, stream>>>(denF, DEN_TOT);
    k_dots<<<dim3(bn / 256, 7), 256, 0, stream>>>(X, xsq, srcF, srcB, DF, DB);
    k_argmin<<<dim3(bn / 256, 2), 256, 0, stream>>>(DF, DB, wfg, wbg, asgF, asgB, denF, denB);
    k_reduce1<<<dim3(NPIX / 128, CE / 128, NB * 2), 128, 0, stream>>>(X, asgF, asgB, PF, PB);
    k_reduce2f<<<(naF + naB + 255) / 256, 256, 0, stream>>>(
        PF, denF, srcF, dstF, naF, PB, denB, srcB, dstB, naB);
    double* tmp;
    tmp = srcF; srcF = dstF; dstF = tmp;
    tmp = srcB; srcB = dstB; dstB = tmp;
  }
  double* fgC = srcF; double* bgC = srcB;

  // ---- layers ----
  for (int l = 0; l < NLAYERS; ++l) {
    const float* bv_l   = bv   + l * CE;
    const float* boff_l = boff + l * 216;
    const float* ba_l   = ba   + l * 108;
    const float* bout_l = bout + l * CE;

    k_cvtA<<<cvtBlocks, 256, 0, stream>>>(X, POS, (const float*)nullptr, QB);
    k_cvtA<<<cvtBlocks, 256, 0, stream>>>(X, (const float*)nullptr, notp, VBin);
    k_gemm_bf<<<dim3(3, 128), 256, 0, stream>>>(VBin, WT[l][0], bv_l, V, (unsigned short*)nullptr,
                                                bn, CE, 384, 0);
    k_gemm_bf<<<dim3(2, 128), 256, 0, stream>>>(QB, WT[l][1], boff_l, (float*)nullptr, OFFb,
                                                bn, CE, 216, 0);
    k_gemm_bf<<<dim3(1, 128), 256, 0, stream>>>(QB, WT[l][2], ba_l, (float*)nullptr, AWb,
                                                bn, CE, 108, 0);
    k_softmax<<<(int)((BN * NH + 255) / 256), 256, 0, stream>>>(AWb);
    k_sample<<<cvtBlocks, 256, 0, stream>>>(V, OFFb, AWb, T1b);
    k_gemm_bf<<<dim3(3, 128), 256, 0, stream>>>(T1b, WT[l][3], bout_l, T2, (unsigned short*)nullptr,
                                                bn, CE, 384, 0);
    k_ln<<<bn, 64, 0, stream>>>(X, T2, ln1g + l * CE, ln1b + l * CE);
    k_cvtA<<<cvtBlocks, 256, 0, stream>>>(X, (const float*)nullptr, (const float*)nullptr, XB);
    k_gemm_bf<<<dim3(9, 128), 256, 0, stream>>>(XB, WT[l][4], (const float*)nullptr,
                                                (float*)nullptr, Zbf, bn, CE, 1152, 1);
    k_gemm_bf<<<dim3(3, 128), 256, 0, stream>>>(Zbf, WT[l][5], (const float*)nullptr,
                                                T2, (unsigned short*)nullptr, bn, 1152, 384, 0);
    k_ln<<<bn, 64, 0, stream>>>(X, T2, ln2g + l * CE, ln2b + l * CE);
  }

  k_out<<<(int)(((long)NB * (NPIX + KFG + KBG) * CE + 255) / 256), 256, 0, stream>>>(
      X, fgC, bgC, out);
}